// Round 8
// baseline (1509.580 us; speedup 1.0000x reference)
//
#include <hip/hip_runtime.h>
#include <hip/hip_bf16.h>
#include <stdint.h>

#define G_ 4
#define E_ 16
#define C_ 2048
#define H_ 512
#define F_ 2048

typedef __attribute__((ext_vector_type(8))) short bf16x8;
typedef __attribute__((ext_vector_type(4))) float f32x4;
typedef __attribute__((ext_vector_type(16))) float f32x16;
typedef uint32_t u32_glb __attribute__((address_space(1)));
typedef uint32_t u32_lds __attribute__((address_space(3)));

__device__ __forceinline__ ushort f2bf(float f){
  uint u = __float_as_uint(f);
  return (ushort)((u + 0x7FFFu + ((u >> 16) & 1u)) >> 16);  // RNE
}

__device__ __forceinline__ bf16x8 pack8(f32x4 a, f32x4 b){
  union { bf16x8 v; uint u[4]; } p;
  p.u[0] = (uint)f2bf(a[0]) | ((uint)f2bf(a[1]) << 16);
  p.u[1] = (uint)f2bf(a[2]) | ((uint)f2bf(a[3]) << 16);
  p.u[2] = (uint)f2bf(b[0]) | ((uint)f2bf(b[1]) << 16);
  p.u[3] = (uint)f2bf(b[2]) | ((uint)f2bf(b[3]) << 16);
  return p.v;
}

__device__ __forceinline__ f32x4 gelu4(f32x4 v){
  f32x4 r;
  #pragma unroll
  for (int i = 0; i < 4; ++i){
    float t = v[i];
    r[i] = 0.5f * t * (1.0f + erff(t * 0.7071067811865475f));  // exact GELU
  }
  return r;
}

// transpose + fp32->bf16 convert: src [E][R][C] fp32 -> dst [E][C][R] bf16
__global__ void transpose_cvt(const float* __restrict__ src, ushort* __restrict__ dst,
                              int R, int C){
  __shared__ float tile[64][65];
  int c0 = blockIdx.x * 64, r0 = blockIdx.y * 64, e = blockIdx.z;
  int tx = threadIdx.x & 63, ty = threadIdx.x >> 6;   // 256 threads
  const float* s = src + (size_t)e * R * C;
  #pragma unroll
  for (int it = 0; it < 16; ++it){
    int row = ty + it * 4;
    tile[row][tx] = s[(size_t)(r0 + row) * C + (c0 + tx)];
  }
  __syncthreads();
  ushort* d = dst + (size_t)e * C * R;
  #pragma unroll
  for (int it = 0; it < 16; ++it){
    int row = ty + it * 4;
    d[(size_t)(c0 + row) * R + (r0 + tx)] = f2bf(tile[tx][row]);
  }
}

// ffn_fused6: 32x32x16 MFMA version. 512 thr, 8 waves = 4 tg(32 tok) x 2 kh.
// GEMM1 K-split partial (one 32x32 tile, 16 MFMA), sEx exchange (D-rows 0-15 vs
// 16-31 = regs 0-7 vs 8-15), GELU on own f-half (8 vals), pa exchange via sPa,
// GEMM2 full-K on own 256-h half (8 tiles x 2 ksteps, 16 MFMA, 16 b128 W2 reads).
__global__ __launch_bounds__(512, 2) void ffn_fused6(
    const float* __restrict__ x,      // [G][E][C][H] fp32
    const float* __restrict__ b1,     // [E][F] fp32
    const float* __restrict__ b2,     // [E][H] fp32
    const ushort* __restrict__ w1t,   // [E][F][H] bf16
    const ushort* __restrict__ w2t,   // [E][H][F] bf16
    float* __restrict__ out){         // [G][E][C][H] fp32
  __shared__ ushort sW1[2][32 * 512];   // 64 KB, linear, content XOR-swizzled (row&7)<<4
  __shared__ ushort sW2b[2][512 * 32];  // 64 KB, [h] 64B rows, 16B slots q ^ ((h>>1)&3)
  __shared__ f32x4  sEx[2 * 8 * 64];    // 16 KB, [plane][tg*2+kh][lane]
  __shared__ uchar  sPaB[4 * 4096];     //  8 KB, [tg][slot 0..3][tok] 16B

  const int tid  = threadIdx.x;
  const int lane = tid & 63;
  const int wv   = tid >> 6;          // 0..7
  const int hi   = lane >> 5;         // 0/1
  const int t31  = lane & 31;
  const int tg   = wv >> 1;           // token group (32 tokens)
  const int kh   = wv & 1;            // K-half (GEMM1) / h-half (GEMM2)

  // XCD-aware bijective swizzle: 1024 blocks = 8 XCDs x 128
  const int bid  = (blockIdx.x & 7) * 128 + (blockIdx.x >> 3);
  const int e    = bid >> 6;
  const int mb   = bid & 63;
  const int n0   = mb * 128;
  const int g    = n0 >> 11;
  const int c0   = n0 & (C_ - 1);

  // X fragments: lane holds token c0+tg*32+t31, k = kh*256 + kk*16 + hi*8 + j
  const float* xr = x + ((size_t)(g * E_ + e) * C_ + (c0 + tg * 32 + t31)) * H_
                  + kh * 256 + hi * 8;
  bf16x8 xf[16];
  #pragma unroll
  for (int kk = 0; kk < 16; ++kk){
    f32x4 fa = *(const f32x4*)(xr + kk * 16);
    f32x4 fb = *(const f32x4*)(xr + kk * 16 + 4);
    xf[kk] = pack8(fa, fb);
  }

  f32x16 acc2[8];                     // 32 tok x 256 h = 8 tiles -> 128 regs
  #pragma unroll
  for (int ht = 0; ht < 8; ++ht)
    #pragma unroll
    for (int q = 0; q < 16; ++q) acc2[ht][q] = 0.f;

  const ushort* w1e = w1t + (size_t)e * F_ * H_;
  const ushort* w2e = w2t + (size_t)e * H_ * F_;
  uint4 w2r[4];

  #define STAGE_W1(F0, NB)                                                       \
    { _Pragma("unroll")                                                          \
      for (int it = 0; it < 4; ++it){                                            \
        int row = wv + it * 8;                                                   \
        const ushort* gsrc = w1e + (size_t)((F0) + row) * H_                     \
                           + (((lane * 16) ^ ((row & 7) << 4)) >> 1);            \
        __builtin_amdgcn_global_load_lds((const u32_glb*)(uintptr_t)gsrc,        \
            (u32_lds*)(uintptr_t)(&sW1[(NB)][row * 512]), 16, 0, 0);             \
      } }
  // W2: thread t covers rows h = 128i + (t>>2), f-quad q = t&3 (16B each)
  #define STAGE_W2_ISSUE(F0)                                                     \
    { _Pragma("unroll")                                                          \
      for (int i = 0; i < 4; ++i){                                               \
        int h = 128 * i + (tid >> 2);                                            \
        w2r[i] = *(const uint4*)(w2e + (size_t)h * F_ + (F0) + (tid & 3) * 8);   \
      } }
  #define STAGE_W2_WRITE(NB)                                                     \
    { _Pragma("unroll")                                                          \
      for (int i = 0; i < 4; ++i){                                               \
        int h = 128 * i + (tid >> 2);                                            \
        int slot = (tid & 3) ^ ((h >> 1) & 3);                                   \
        *(uint4*)((char*)&sW2b[(NB)][0] + h * 64 + slot * 16) = w2r[i];          \
      } }

  // ---- prologue: stage chunk 0 ----
  STAGE_W2_ISSUE(0)
  STAGE_W1(0, 0)
  STAGE_W2_WRITE(0)
  asm volatile("s_waitcnt vmcnt(0)" ::: "memory");
  __syncthreads();

  const char* a1base = (const char*)&sW1[0][0];      // indexed per-buffer below
  const int   arow   = t31;                          // A row = f (lane&31)
  const int   sw1k   = (arow & 7) << 4;

  for (int ch = 0; ch < 64; ++ch){
    const int f0  = ch * 32;
    const int cur = ch & 1, nxt = cur ^ 1;
    if (ch < 63){
      STAGE_W2_ISSUE(f0 + 32)
      STAGE_W1(f0 + 32, nxt)
    }

    // ---- GEMM1 partial: one 32x32 tile over own K-half (16 MFMA) ----
    f32x16 acc1;
    #pragma unroll
    for (int q = 0; q < 16; ++q) acc1[q] = 0.f;
    {
      const char* rb = a1base + cur * (32 * 1024) + arow * 1024;
      __builtin_amdgcn_s_setprio(1);
      #pragma unroll
      for (int kk = 0; kk < 16; ++kk){
        int kb = (kh * 512 + kk * 32 + hi * 16) ^ sw1k;
        bf16x8 afr = *(const bf16x8*)(rb + kb);
        acc1 = __builtin_amdgcn_mfma_f32_32x32x16_bf16(afr, xf[kk], acc1, 0, 0, 0);
      }
      __builtin_amdgcn_s_setprio(0);
    }

    // ---- sEx: publish foreign f-half partial (regs 8-15 for kh=0, 0-7 for kh=1)
    {
      f32x4 e0, e1;
      if (kh == 0){
        e0 = (f32x4){acc1[8],acc1[9],acc1[10],acc1[11]};
        e1 = (f32x4){acc1[12],acc1[13],acc1[14],acc1[15]};
      } else {
        e0 = (f32x4){acc1[0],acc1[1],acc1[2],acc1[3]};
        e1 = (f32x4){acc1[4],acc1[5],acc1[6],acc1[7]};
      }
      int exb = (tg * 2 + kh) * 64 + lane;
      sEx[exb]       = e0;
      sEx[512 + exb] = e1;
    }
    __syncthreads();                   // B1

    if (ch < 63) STAGE_W2_WRITE(nxt)   // LDS writes to next buffer (safe here)

    // ---- finalize own f-half + bias + exact GELU + pack -> sPa ----
    {
      int exr = (tg * 2 + (1 - kh)) * 64 + lane;
      f32x4 p0 = sEx[exr], p1 = sEx[512 + exr];
      f32x4 o0, o1;
      if (kh == 0){
        o0 = (f32x4){acc1[0],acc1[1],acc1[2],acc1[3]};
        o1 = (f32x4){acc1[4],acc1[5],acc1[6],acc1[7]};
      } else {
        o0 = (f32x4){acc1[8],acc1[9],acc1[10],acc1[11]};
        o1 = (f32x4){acc1[12],acc1[13],acc1[14],acc1[15]};
      }
      o0 = o0 + p0; o1 = o1 + p1;
      // lane's f (within chunk) = kh*16 + {0..3}+4hi (o0) and +8 (o1)
      const float* b1p = b1 + (size_t)e * F_ + f0 + kh * 16 + 4 * hi;
      f32x4 ba = *(const f32x4*)(b1p);
      f32x4 bb = *(const f32x4*)(b1p + 8);
      f32x4 g0 = gelu4(o0 + ba), g1 = gelu4(o1 + bb);
      uint4 pw;
      pw.x = (uint)f2bf(g0[0]) | ((uint)f2bf(g0[1]) << 16);
      pw.y = (uint)f2bf(g0[2]) | ((uint)f2bf(g0[3]) << 16);
      pw.z = (uint)f2bf(g1[0]) | ((uint)f2bf(g1[1]) << 16);
      pw.w = (uint)f2bf(g1[2]) | ((uint)f2bf(g1[3]) << 16);
      // slot (kh*2+hi), tok t31: 16B = [P1 (f +0..3+4hi) | P2 (f +8..11+4hi)]
      *(uint4*)(sPaB + tg * 4096 + (kh * 2 + hi) * 512 + t31 * 16) = pw;
    }
    __syncthreads();                   // B2

    // ---- assemble full-K A-frags from sPa; GEMM2 on own 256-h half ----
    {
      const uchar* pab = sPaB + tg * 4096 + t31 * 16 + hi * 8;
      bf16x8 af[2];
      #pragma unroll
      for (int s = 0; s < 2; ++s){
        uint2 u0 = *(const uint2*)(pab + (s * 2 + 0) * 512);
        uint2 u1 = *(const uint2*)(pab + (s * 2 + 1) * 512);
        union { bf16x8 v; uint u[4]; } A;
        A.u[0] = u0.x; A.u[1] = u0.y; A.u[2] = u1.x; A.u[3] = u1.y;
        af[s] = A.v;                   // k-slot j -> f = f0 + s*16 + hi*8 + j
      }
      const int key2 = (t31 >> 1) & 3;
      const char* wbase = (const char*)&sW2b[cur][0];
      __builtin_amdgcn_s_setprio(1);
      #pragma unroll
      for (int ht = 0; ht < 8; ++ht){
        const char* wb = wbase + (kh * 256 + ht * 32 + t31) * 64;
        #pragma unroll
        for (int s = 0; s < 2; ++s){
          bf16x8 bf = *(const bf16x8*)(wb + 16 * ((s * 2 + hi) ^ key2));
          acc2[ht] = __builtin_amdgcn_mfma_f32_32x32x16_bf16(af[s], bf, acc2[ht], 0, 0, 0);
        }
      }
      __builtin_amdgcn_s_setprio(0);
    }

    asm volatile("s_waitcnt vmcnt(0)" ::: "memory");  // W1 DMA landed
    __syncthreads();                   // B3
  }

  // ---- epilogue: D2 col = h (t31), row = (q&3)+8*(q>>2)+4*hi (token slot)
  const size_t obase = (size_t)(g * E_ + e) * C_ + c0 + tg * 32;
  #pragma unroll
  for (int ht = 0; ht < 8; ++ht){
    const int h  = kh * 256 + ht * 32 + t31;
    const float bb = b2[(size_t)e * H_ + h];
    #pragma unroll
    for (int q = 0; q < 16; ++q){
      const int row = (q & 3) + 8 * (q >> 2) + 4 * hi;
      out[(obase + row) * H_ + h] = acc2[ht][q] + bb;
    }
  }
  #undef STAGE_W1
  #undef STAGE_W2_ISSUE
  #undef STAGE_W2_WRITE
}

extern "C" void kernel_launch(void* const* d_in, const int* in_sizes, int n_in,
                              void* d_out, int out_size, void* d_ws, size_t ws_size,
                              hipStream_t stream){
  const float *x = nullptr, *b1 = nullptr, *b2 = nullptr;
  const float* w12[2] = {nullptr, nullptr}; int nw = 0;
  for (int i = 0; i < n_in; ++i){
    long s = (long)in_sizes[i];
    if      (s == (long)G_ * E_ * C_ * H_) x = (const float*)d_in[i];
    else if (s == (long)E_ * H_ * F_) { if (nw < 2) w12[nw++] = (const float*)d_in[i]; }
    else if (s == (long)E_ * F_) b1 = (const float*)d_in[i];
    else if (s == (long)E_ * H_) b2 = (const float*)d_in[i];
  }
  const float* w1 = w12[0];
  const float* w2 = w12[1];
  if (!x || !w1 || !w2 || !b1 || !b2){
    x  = (const float*)d_in[0];
    w1 = (const float*)d_in[1];
    b1 = (const float*)d_in[2];
    w2 = (const float*)d_in[3];
    b2 = (const float*)d_in[4];
  }

  ushort* w1t = (ushort*)d_ws;                       // [E][F][H] bf16
  ushort* w2t = w1t + (size_t)E_ * F_ * H_;          // [E][H][F] bf16

  transpose_cvt<<<dim3(F_ / 64, H_ / 64, E_), dim3(256), 0, stream>>>(w1, w1t, H_, F_);
  transpose_cvt<<<dim3(H_ / 64, F_ / 64, E_), dim3(256), 0, stream>>>(w2, w2t, F_, H_);

  ffn_fused6<<<dim3(E_ * 64), dim3(512), 0, stream>>>(x, b1, b2, w1t, w2t, (float*)d_out);
}